// Round 7
// baseline (422.306 us; speedup 1.0000x reference)
//
#include <hip/hip_runtime.h>
#include <cstdint>
#include <cstddef>

typedef unsigned short ushort;
typedef __attribute__((ext_vector_type(8))) short short8;    // 8 x bf16 (4 VGPRs)
typedef __attribute__((ext_vector_type(16))) float f32x16;   // 32x32 accumulator

__device__ __forceinline__ float bf2f(ushort u) {
  union { unsigned u; float f; } c; c.u = ((unsigned)u) << 16; return c.f;
}
__device__ __forceinline__ ushort f2bf(float f) {
  union { float f; unsigned u; } c; c.f = f;
  unsigned u = c.u;
  return (ushort)((u + 0x7fffu + ((u >> 16) & 1u)) >> 16);   // RNE
}

#define G2L(g, l) __builtin_amdgcn_global_load_lds( \
    (const __attribute__((address_space(1))) void*)(g), \
    (__attribute__((address_space(3))) void*)(l), 16, 0, 0)

#define BARRIER() do { asm volatile("" ::: "memory"); __builtin_amdgcn_s_barrier(); asm volatile("" ::: "memory"); } while (0)
// counted LDS wait (DS completes in order); rule 18: sched_barrier(0) so MFMAs can't hoist above.
#define LGKMC(N) do { asm volatile("s_waitcnt lgkmcnt(%0)" :: "n"(N) : "memory"); __builtin_amdgcn_sched_barrier(0); } while (0)

__device__ __forceinline__ unsigned ldsoff(const void* p) {
  return (unsigned)(unsigned long long)(__attribute__((address_space(3))) const void*)p;
}

// ---------------- MFMA GEMM: C[M,N] = A[M,K] . B[N,K]^T (+bias) ----------------
// R7: 2 blocks/CU. BMx128 tile (BM=256 or 128), BK=32, 4 waves (256 thr),
// dbuf LDS = (BM+128)*32*2B*2 = 48KB/32KB -> 2 blocks co-resident per CU, all
// grids 512. The single-block pipeline (R1-R6) plateaued ~900cyc above the LDS
// wall because every barrier/first-read bubble idled the whole CU; a second
// independent block fills those slots (its reads flow while we sit in barriers).
// Wave tiles keep the proven read ratio: BM=256 -> 128x64 (MF=4,NF=2).
// Schedule per K-tile t (2 h-groups, counted waits, R6 protocol):
//   ISSUE(s1,h1) -> lgkm(RD): h0 landed -> MFMA(s0) || h1 drain -> lgkm(0)
//   BARRIER(WAR) -> STAGE(t+2->cur) -> vmcnt(LPS) -> BARRIER(RAW)
//   ISSUE(s0, h0 of t+1 from cur^1) -> MFMA(s1) || next h0 drain
// LDS layout (BK=32: 64B rows = 4 chunks): ROW-PAIR swizzle. Row-pair p=r>>1 at
// byte p*128; (r,c) at slot ((r&1)*4 + c + (p&7))&7 (16B slots). Staging inverts
// it in the per-lane GLOBAL source: thread (rp=tid>>3, s=tid&7) -> d=(s-rp)&7,
// row=rp*2+(d>>2), chunk=d&3; G2L dest stays linear (tid*16). Read side: lane
// needs chunk cc=2h+hb of row r -> slot = ((r&1)*4 + cc + ((r>>1)&7))&7.
// 8 consecutive lanes hit 8 distinct 16B groups (2-way per 16 lanes = same
// residue as the verified BK=64 rotation).
// MODE 0: bias fp32, write bf16 / MODE 1,2: write bf16 / MODE 3: bias, fp32 split @512.
struct MArgs {
  const ushort* A; int lda; long asz;
  const ushort* B; int ldb; long bsz;
  void* C; int ldc; long csz;
  int K;
  const float* bias;
  float* C2;
};

template<int MODE, int BM>
__launch_bounds__(256, 2)
__global__ void mfma_gemm(MArgs g) {
  constexpr int BN = 128;
  constexpr int WMSZ = BM / 2;       // 2 waves along M: 128 or 64
  constexpr int MF = WMSZ / 32;      // 4 or 2
  constexpr int NF = 2;              // 2 waves along N, 64 each
  constexpr int NAG = BM / 64;       // A staging groups (64 rows each): 4 or 2
  constexpr int NBG = BN / 64;       // 2
  constexpr int LPS = NAG + NBG;     // G2L per thread per K-tile (6 or 4)
  constexpr int RD = MF + NF;        // ds_reads per h-group (6 or 4)

  __shared__ __attribute__((aligned(16))) ushort As[2][BM * 32];
  __shared__ __attribute__((aligned(16))) ushort Bs[2][BN * 32];

  const int tid = threadIdx.x;
  const int lane = tid & 63;
  const int wave = tid >> 6;
  const int z = blockIdx.z;

  // XCD-aware swizzle (nwg = 512 in all stages, multiple of 8 -> bijective)
  int bx = blockIdx.x, by = blockIdx.y;
  {
    const int gx = gridDim.x;
    const int nwg = gx * gridDim.y;
    int wg = by * gx + bx;
    wg = (wg & 7) * (nwg >> 3) + (wg >> 3);
    bx = wg % gx; by = wg / gx;
  }
  const long m0 = (long)by * BM;
  const long n0 = (long)bx * BN;
  const ushort* Ab = g.A + (long)z * g.asz;
  const ushort* Bb = g.B + (long)z * g.bsz;

  // ---- staging source (row-pair swizzle inversion, see header)
  const int rp = tid >> 3;                 // row-pair in 64-row group (0..31)
  const int sd = ((tid & 7) - rp) & 7;
  const int srcrow = rp * 2 + (sd >> 2);   // row within 64-row group
  const int scol = (sd & 3) * 8;           // elem offset (chunk*8)
  const ushort* ga[NAG];
  const ushort* gb[NBG];
#pragma unroll
  for (int q = 0; q < NAG; ++q) ga[q] = Ab + (m0 + q * 64 + srcrow) * (long)g.lda + scol;
#pragma unroll
  for (int q = 0; q < NBG; ++q) gb[q] = Bb + (n0 + q * 64 + srcrow) * (long)g.ldb + scol;

  // ---- fragment read offsets: lane l reads X[r][chunk cc=2h+hb]
  // byte = (r>>1)*128 + (((r&1)*4 + cc + ((r>>1)&7))&7)*16
  const int l31 = lane & 31, hb = lane >> 5;
  const int wmi = wave >> 1, wni = wave & 1;
  unsigned aoffB[MF]; int arot[MF];
#pragma unroll
  for (int mf = 0; mf < MF; ++mf) {
    const int r = wmi * WMSZ + mf * 32 + l31;
    aoffB[mf] = (unsigned)((r >> 1) * 128);
    arot[mf] = ((r & 1) * 4 + hb + ((r >> 1) & 7));
  }
  unsigned boffB[NF]; int brot[NF];
#pragma unroll
  for (int nf = 0; nf < NF; ++nf) {
    const int r = wni * 64 + nf * 32 + l31;
    boffB[nf] = (unsigned)((r >> 1) * 128);
    brot[nf] = ((r & 1) * 4 + hb + ((r >> 1) & 7));
  }

  f32x16 acc[MF][NF];
#pragma unroll
  for (int mf = 0; mf < MF; ++mf)
#pragma unroll
    for (int nf = 0; nf < NF; ++nf)
#pragma unroll
      for (int r = 0; r < 16; ++r) acc[mf][nf][r] = 0.f;

  auto STAGEF = [&](int buf, int t) {
    const long ko = (long)t * 32;
#pragma unroll
    for (int q = 0; q < NAG; ++q) G2L(ga[q] + ko, &As[buf][q * 2048 + tid * 8]);
#pragma unroll
    for (int q = 0; q < NBG; ++q) G2L(gb[q] + ko, &Bs[buf][q * 2048 + tid * 8]);
  };

  const unsigned abB[2] = { ldsoff(&As[0][0]), ldsoff(&As[1][0]) };
  const unsigned bbB[2] = { ldsoff(&Bs[0][0]), ldsoff(&Bs[1][0]) };
  short8 av[2][MF], bv[2][NF];

  // issue RD asm ds_read_b128 for h-group h into slot s from buffers (ab,bb)
#define ISSUE_H(s, h, ab, bb) do { \
  _Pragma("unroll") for (int mf = 0; mf < MF; ++mf) { \
    unsigned o = (ab) + aoffB[mf] + (unsigned)(((2 * (h) + arot[mf]) & 7) << 4); \
    asm volatile("ds_read_b128 %0, %1" : "=v"(av[s][mf]) : "v"(o)); \
  } \
  _Pragma("unroll") for (int nf = 0; nf < NF; ++nf) { \
    unsigned o = (bb) + boffB[nf] + (unsigned)(((2 * (h) + brot[nf]) & 7) << 4); \
    asm volatile("ds_read_b128 %0, %1" : "=v"(bv[s][nf]) : "v"(o)); \
  } \
} while (0)
#define MFMA_S(s) do { \
  __builtin_amdgcn_s_setprio(1); \
  _Pragma("unroll") for (int mf = 0; mf < MF; ++mf) \
  _Pragma("unroll") for (int nf = 0; nf < NF; ++nf) \
    acc[mf][nf] = __builtin_amdgcn_mfma_f32_32x32x16_bf16(av[s][mf], bv[s][nf], acc[mf][nf], 0, 0, 0); \
  __builtin_amdgcn_s_setprio(0); \
} while (0)

  STAGEF(0, 0);            // tile 0 -> buf 0
  STAGEF(1, 1);            // tile 1 -> buf 1   (nt >= 3 in all stages)
  asm volatile("s_waitcnt vmcnt(%0)" :: "n"(LPS) : "memory");   // tile 0 landed
  BARRIER();
  ISSUE_H(0, 0, abB[0], bbB[0]);   // h0 of tile 0

  const int nt = g.K >> 5;
  for (int t = 0; t < nt; ++t) {
    const int cur = t & 1;
    const unsigned ab = abB[cur], bb = bbB[cur];

    ISSUE_H(1, 1, ab, bb);
    LGKMC(RD);          // h0 landed (h1 in flight)
    MFMA_S(0);          // h0  || h1 drain
    LGKMC(0);           // h1 landed; all reads of buf[cur] done (wave-local)

    if (t + 1 < nt) {
      BARRIER();                                 // WAR gate: buf[cur] fully read block-wide
      if (t + 2 < nt) {
        STAGEF(cur, t + 2);                      // overwrite buf[cur] with tile t+2
        asm volatile("s_waitcnt vmcnt(%0)" :: "n"(LPS) : "memory");  // t+1 landed, t+2 in flight
      } else {
        asm volatile("s_waitcnt vmcnt(0)" ::: "memory");             // t+1 landed
      }
      BARRIER();                                 // RAW gate block-wide
      ISSUE_H(0, 0, abB[cur ^ 1], bbB[cur ^ 1]); // prefetch h0 of tile t+1
    }
    MFMA_S(1);          // h1  || next tile's h0 drain
  }
#undef ISSUE_H
#undef MFMA_S

  // ---- epilogue: C/D map (m74/m101): col=lane&31, row=(reg&3)+8*(reg>>2)+4*(lane>>5)
  const int cc = l31;
  const int rbase = 4 * hb;
  ushort* Cu = (ushort*)g.C + (long)z * g.csz;
  float* Cf = (float*)g.C;
#pragma unroll
  for (int mf = 0; mf < MF; ++mf) {
#pragma unroll
    for (int nf = 0; nf < NF; ++nf) {
      const long col = n0 + wni * 64 + nf * 32 + cc;
      float bsv = 0.f;
      if (MODE == 0 || MODE == 3) bsv = g.bias[col];
#pragma unroll
      for (int r = 0; r < 16; ++r) {
        const long row = m0 + wmi * WMSZ + mf * 32 + (r & 3) + 8 * (r >> 2) + rbase;
        float v = acc[mf][nf][r] + bsv;
        if (MODE == 3) {
          float* dst = (col < 512) ? (Cf + row * 512 + col) : (g.C2 + row * 512 + (col - 512));
          *dst = v;
        } else {
          Cu[row * (long)g.ldc + col] = f2bf(v);
        }
      }
    }
  }
}

// ---------------- converts ----------------
__global__ void cvt_x6(const float* x0, const float* x1, const float* x2,
                       const float* x3, const float* x4, const float* x5, ushort* X) {
  const long m = blockIdx.y;
  const int c4 = (blockIdx.x * 256 + threadIdx.x) * 4;  // 0..3071
  const int p = c4 >> 9, d = c4 & 511;
  const float* xp;
  switch (p) {
    case 0: xp = x0; break; case 1: xp = x1; break; case 2: xp = x2; break;
    case 3: xp = x3; break; case 4: xp = x4; break; default: xp = x5; break;
  }
  float4 v = *(const float4*)(xp + m * 512 + d);
  ushort4 o; o.x = f2bf(v.x); o.y = f2bf(v.y); o.z = f2bf(v.z); o.w = f2bf(v.w);
  *(ushort4*)(X + m * 3072 + c4) = o;
}

__device__ __forceinline__ int chunk_map(int c) { return (c == 0) ? 0 : (c == 1) ? 2 : (c == 2) ? 4 : 5; }

__global__ void cvt_w4(const float* W, ushort* Wq4) {
  const long r = blockIdx.y;                       // 0..2047
  const int c4 = (blockIdx.x * 256 + threadIdx.x) * 4;
  const long wr = (long)chunk_map((int)(r >> 9)) * 512 + (r & 511);
  float4 v = *(const float4*)(W + wr * 3072 + c4);
  ushort4 o; o.x = f2bf(v.x); o.y = f2bf(v.y); o.z = f2bf(v.z); o.w = f2bf(v.w);
  *(ushort4*)(Wq4 + r * 3072 + c4) = o;
}

__global__ void cvt_wout(const float* W, ushort* Wo) {
  const long r = blockIdx.y;
  const int c4 = threadIdx.x * 4;
  float4 v = *(const float4*)(W + r * 1024 + c4);
  ushort4 o; o.x = f2bf(v.x); o.y = f2bf(v.y); o.z = f2bf(v.z); o.w = f2bf(v.w);
  *(ushort4*)(Wo + r * 1024 + c4) = o;
}

__global__ void mk_bias4(const float* bqkv, float* b4) {
  const int n = blockIdx.x * 256 + threadIdx.x;    // 0..2047
  b4[n] = bqkv[chunk_map(n >> 9) * 512 + (n & 511)];
}

// ---------------- V transpose: Vt_b[n][k] = QKV[b*2048+k][1024+n] ----------------
// 16B/lane global loads AND stores; LDS tile [64][68] (136B stride spreads banks).
__global__ void transpose_v(const ushort* QKV, ushort* Vt) {
  __shared__ ushort t2[64][68];
  const int tid = threadIdx.x;
  const int k0 = blockIdx.x * 64, n0 = blockIdx.y * 64, b = blockIdx.z;
  const ushort* src = QKV + (long)b * 2048 * 2048 + 1024;
#pragma unroll
  for (int i = 0; i < 2; ++i) {
    const int slot = i * 256 + tid;                // 0..511
    const int kr = slot >> 3, nc = slot & 7;
    short8 v = *(const short8*)(src + (long)(k0 + kr) * 2048 + (n0 + nc * 8));
#pragma unroll
    for (int j = 0; j < 8; ++j) t2[nc * 8 + j][kr] = (ushort)v[j];
  }
  __syncthreads();
  ushort* dst = Vt + (long)b * 1024 * 2048;
#pragma unroll
  for (int i = 0; i < 2; ++i) {
    const int slot = i * 256 + tid;
    const int nr = slot >> 3, kc = slot & 7;
    short8 v;
#pragma unroll
    for (int j = 0; j < 8; ++j) v[j] = (short)t2[nr][kc * 8 + j];
    *(short8*)(dst + (long)(n0 + nr) * 2048 + (k0 + kc * 8)) = v;
  }
}

// ---------------- softmax: lane owns one contiguous 64B chunk (32 elems) ----------------
__launch_bounds__(256)
__global__ void softmax_rows(ushort* S, const int* mask) {
  const int lane = threadIdx.x & 63;
  const int wave = threadIdx.x >> 6;
  const long row = (long)blockIdx.x * 4 + wave;            // 0..8191
  const int* m = mask + (row >> 11) * 2048 + lane * 32;
  ushort* s = S + row * 2048 + lane * 32;
  const float scale = 0.04419417382415922f;                // 512^-0.5

  short8 raw[4];
#pragma unroll
  for (int i = 0; i < 4; ++i) raw[i] = *(const short8*)(s + i * 8);
  int4 mi[8];
#pragma unroll
  for (int i = 0; i < 8; ++i) mi[i] = *(const int4*)(m + i * 4);

  float v[32];
  int mk[32];
#pragma unroll
  for (int i = 0; i < 8; ++i) {
    mk[i * 4 + 0] = mi[i].x; mk[i * 4 + 1] = mi[i].y;
    mk[i * 4 + 2] = mi[i].z; mk[i * 4 + 3] = mi[i].w;
  }
#pragma unroll
  for (int i = 0; i < 32; ++i) v[i] = bf2f((ushort)raw[i >> 3][i & 7]) * scale;

  float mx = -INFINITY;
#pragma unroll
  for (int i = 0; i < 32; ++i) if (!mk[i]) mx = fmaxf(mx, v[i]);
#pragma unroll
  for (int off = 32; off; off >>= 1) mx = fmaxf(mx, __shfl_xor(mx, off));

  float sum = 0.f;
#pragma unroll
  for (int i = 0; i < 32; ++i) {
    float e = mk[i] ? 0.f : __expf(v[i] - mx);
    v[i] = e;
    sum += e;
  }
#pragma unroll
  for (int off = 32; off; off >>= 1) sum += __shfl_xor(sum, off);

  float r = 1.f / sum;
  short8 out[4];
#pragma unroll
  for (int i = 0; i < 32; ++i) out[i >> 3][i & 7] = (short)f2bf(v[i] * r);
#pragma unroll
  for (int i = 0; i < 4; ++i) *(short8*)(s + i * 8) = out[i];
}

// ---------------- launcher ----------------
extern "C" void kernel_launch(void* const* d_in, const int* in_sizes, int n_in,
                              void* d_out, int out_size, void* d_ws, size_t ws_size,
                              hipStream_t stream) {
  const float* qr = (const float*)d_in[0];
  const float* qi = (const float*)d_in[1];
  const float* kr = (const float*)d_in[2];
  const float* ki = (const float*)d_in[3];
  const float* vr = (const float*)d_in[4];
  const float* vi = (const float*)d_in[5];
  const int* pm = (const int*)d_in[6];
  const float* Wqkv = (const float*)d_in[7];
  const float* bqkv = (const float*)d_in[8];
  const float* Wout = (const float*)d_in[9];
  const float* bout = (const float*)d_in[10];
  float* out = (float*)d_out;

  // ws layout (bytes):
  char* base = (char*)d_ws;
  ushort* QKV   = (ushort*)(base);                         // 8192x2048 bf16   33,554,432
  ushort* Wq4   = (ushort*)(base + 33554432);              // 2048x3072 bf16   12,582,912
  ushort* Wo    = (ushort*)(base + 46137344);              // 1024x1024 bf16    2,097,152
  float*  b4    = (float*) (base + 48234496);              // 2048 fp32             8,192
  char*   uni   = base + 48242688;
  ushort* Xbf   = (ushort*)(uni);                          // 8192x3072 bf16   50,331,648 (dies after stage1)
  ushort* Vt    = (ushort*)(uni);                          // 4x1024x2048 bf16 16,777,216
  ushort* S     = (ushort*)(uni + 16777216);               // 4x2048x2048 bf16 33,554,432
  ushort* AO    = (ushort*)(uni + 50331648);               // 8192x1024 bf16   16,777,216
  // total 115,351,552 bytes

  // converts
  cvt_x6<<<dim3(3, 8192), 256, 0, stream>>>(qr, qi, kr, ki, vr, vi, Xbf);
  cvt_w4<<<dim3(3, 2048), 256, 0, stream>>>(Wqkv, Wq4);
  cvt_wout<<<dim3(1, 1024), 256, 0, stream>>>(Wout, Wo);
  mk_bias4<<<8, 256, 0, stream>>>(bqkv, b4);

  // stage 1: QKV = Xbf(8192x3072) . Wq4(2048x3072)^T + b4  -> bf16   [grid 512 = 2 blocks/CU]
  {
    MArgs a{};
    a.A = Xbf; a.lda = 3072; a.asz = 0;
    a.B = Wq4; a.ldb = 3072; a.bsz = 0;
    a.C = QKV; a.ldc = 2048; a.csz = 0;
    a.K = 3072; a.bias = b4;
    mfma_gemm<0, 256><<<dim3(16, 32, 1), 256, 0, stream>>>(a);
  }

  // V transpose (reads QKV cols 1024..2047)
  transpose_v<<<dim3(32, 16, 4), 256, 0, stream>>>(QKV, Vt);

  // stage 2: S_b = Q_b(2048x512) . K_b(2048x512)^T  -> bf16 (raw scores)  [grid 512]
  {
    MArgs a{};
    a.A = QKV;        a.lda = 2048; a.asz = (long)2048 * 2048;
    a.B = QKV + 512;  a.ldb = 2048; a.bsz = (long)2048 * 2048;
    a.C = S;          a.ldc = 2048; a.csz = (long)2048 * 2048;
    a.K = 512;
    mfma_gemm<1, 256><<<dim3(16, 8, 4), 256, 0, stream>>>(a);
  }

  // stage 3: softmax rows in place (scale + mask + exp + norm)
  softmax_rows<<<2048, 256, 0, stream>>>(S, pm);

  // stage 4: AO_b = P_b(2048x2048) . Vt_b(1024x2048)^T  -> bf16   [BM=128, grid 512]
  {
    MArgs a{};
    a.A = S;  a.lda = 2048; a.asz = (long)2048 * 2048;
    a.B = Vt; a.ldb = 2048; a.bsz = (long)1024 * 2048;
    a.C = AO; a.ldc = 1024; a.csz = (long)2048 * 1024;
    a.K = 2048;
    mfma_gemm<2, 128><<<dim3(8, 16, 4), 256, 0, stream>>>(a);
  }

  // stage 5: out = AO(8192x1024) . Wo(1024x1024)^T + bout -> fp32 split   [BM=128, grid 512]
  {
    MArgs a{};
    a.A = AO; a.lda = 1024; a.asz = 0;
    a.B = Wo; a.ldb = 1024; a.bsz = 0;
    a.C = out; a.ldc = 512; a.csz = 0;
    a.C2 = out + (long)8192 * 512;
    a.K = 1024; a.bias = bout;
    mfma_gemm<3, 128><<<dim3(8, 64, 1), 256, 0, stream>>>(a);
  }
}